// Round 27
// baseline (241.757 us; speedup 1.0000x reference)
//
#include <hip/hip_runtime.h>
#include <hip/hip_bf16.h>

#define T_DIM 4096
#define B_DIM 4

typedef unsigned short u16;
typedef __attribute__((ext_vector_type(4))) short s16x4;
typedef __attribute__((ext_vector_type(8))) short short8;
typedef __attribute__((ext_vector_type(8))) __bf16 bf16x8;
typedef __attribute__((ext_vector_type(4))) float f32x4;

static __device__ __forceinline__ u16 f2bf(float f) {
    union { float f; unsigned int u; } v; v.f = f;
    unsigned int u = v.u;
    u += 0x7FFFu + ((u >> 16) & 1u);   // RNE
    return (u16)(u >> 16);
}

static __device__ __forceinline__ f32x4 mfma_k32(short8 a, short8 b, f32x4 c) {
    return __builtin_amdgcn_mfma_f32_16x16x32_bf16(
        __builtin_bit_cast(bf16x8, a), __builtin_bit_cast(bf16x8, b), c, 0, 0, 0);
}
static __device__ __forceinline__ f32x4 mfma_k16(s16x4 a, s16x4 b, f32x4 c) {
    return __builtin_amdgcn_mfma_f32_16x16x16bf16_1k(a, b, c, 0, 0, 0);
}

// ---------------------------------------------------------------------------
// Kernel 0: transpose + convert weights to bf16 W^T[n][k]
// ---------------------------------------------------------------------------
__global__ __launch_bounds__(256) void wtrans_kernel(
    const float* __restrict__ Wq, const float* __restrict__ Wk,
    const float* __restrict__ Wv, u16* __restrict__ wT) {
    int idx = blockIdx.x * 256 + threadIdx.x;
    int w   = idx >> 16;
    int rem = idx & 65535;
    int k   = rem >> 8;
    int n   = rem & 255;
    const float* W = (w == 0) ? Wq : (w == 1) ? Wk : Wv;
    wT[w * 65536 + n * 256 + k] = f2bf(W[k * 256 + n]);
}

// ---------------------------------------------------------------------------
// Kernel 1: projection GEMM -> FRAGMENT-PACKED outputs.
//  qf/kf (u16): [b][tile=t/16][kc=0..7][lane][e=0..7]
//      = P[b][tile*16 + (lane&15)][kc*32 + (lane>>4)*8 + e]
//  vf  (u16): NF-PAIR layout (one 16B load feeds two k16 B-frags):
//      [b][jt=t/64][h=0..3][nf2=0..7][lane][e=0..7]
//      = V[b][jt*64 + 16*h + 4*(lane>>4) + (e&3)][ (2*nf2 + e/4)*16 + (lane&15) ]
// ---------------------------------------------------------------------------
__global__ __launch_bounds__(256, 4) void proj_kernel(
    const float* __restrict__ X, const u16* __restrict__ wT,
    u16* __restrict__ qf, u16* __restrict__ kf, u16* __restrict__ vfw) {
    const int r0  = blockIdx.x * 16;
    const int wid = threadIdx.x >> 6, lane = threadIdx.x & 63;
    const int lr  = lane & 15, lg = lane >> 4;

    short8 af[8];
    const float* xrow = X + (size_t)(r0 + lr) * 256 + lg * 8;
#pragma unroll
    for (int kc = 0; kc < 8; ++kc) {
        f32x4 xa = *(const f32x4*)(xrow + kc * 32);
        f32x4 xb = *(const f32x4*)(xrow + kc * 32 + 4);
        union { u16 u[8]; short8 v; } t;
#pragma unroll
        for (int e = 0; e < 4; ++e) { t.u[e] = f2bf(xa[e]); t.u[4 + e] = f2bf(xb[e]); }
        af[kc] = t.v;
    }

    for (int w = 0; w < 3; ++w) {
        f32x4 acc[4];
#pragma unroll
        for (int nf = 0; nf < 4; ++nf) acc[nf] = (f32x4){0.f,0.f,0.f,0.f};
        const u16* wbase = wT + w * 65536 + (size_t)(16 * (4 * wid) + lr) * 256 + lg * 8;
#pragma unroll
        for (int kc = 0; kc < 8; ++kc)
#pragma unroll
            for (int nf = 0; nf < 4; ++nf) {
                short8 bfv = *(const short8*)(wbase + nf * 16 * 256 + kc * 32);
                acc[nf] = mfma_k32(af[kc], bfv, acc[nf]);
            }
#pragma unroll
        for (int nf = 0; nf < 4; ++nf)
#pragma unroll
            for (int r = 0; r < 4; ++r) {
                int rg = r0 + 4 * lg + r;
                int t  = rg >> 2, bb = rg & 3;           // X rows are (t, b)
                int d  = 16 * (4 * wid + nf) + lr;
                u16 val = f2bf(acc[nf][r]);
                if (w < 2) {
                    int tile = t >> 4, lrq = t & 15;
                    int kc = d >> 5, lgq = (d >> 3) & 3, e = d & 7;
                    size_t idx = ((((size_t)bb * 256 + tile) * 8 + kc) * 64
                                  + lrq + 16 * lgq) * 8 + e;
                    if (w == 0) qf[idx] = val; else kf[idx] = val;
                } else {
                    int jt = t >> 6, hh = (t >> 4) & 3;
                    int lgv = (t >> 2) & 3, el = t & 3;
                    int nfv = d >> 4, lrv = d & 15;
                    int lanev = lrv + 16 * lgv;
                    size_t idx = (((((size_t)bb * 64 + jt) * 4 + hh) * 8 + (nfv >> 1)) * 64
                                  + lanev) * 8 + (nfv & 1) * 4 + el;
                    vfw[idx] = val;
                }
            }
    }
}

// ---------------------------------------------------------------------------
// Kernel 2: row-sum (sweep-1) standalone, HIGH OCCUPANCY. Grid 1024 = b x
// 256 16-row tiles (heavy-first), 256 thr = 4 waves = j-quarters. ~70 VGPR
// -> multiple blocks/CU (the fused kernel's sweep1 ran at 2 waves/SIMD).
// Writes inv_ws[b][row] = 1/l.
// ---------------------------------------------------------------------------
__global__ __launch_bounds__(256) void lsum_kernel(
    const u16* __restrict__ qf, const u16* __restrict__ kf,
    float* __restrict__ inv_ws) {
    __shared__ float l_sm[16];

    const int blk = blockIdx.x;
    const int xcd = blk & 7;                 // one b per XCD pair
    const int b = xcd >> 1, par = xcd & 1;
    const int idx = blk >> 3;                // 0..127
    const int it16 = 2 * (127 - idx) + par;  // 0..255, heavy-first
    const int i0 = it16 * 16;

    const int wid = threadIdx.x >> 6, lane = threadIdx.x & 63;
    const int h = wid;                       // j-quarter 0..3
    const int lr = lane & 15, lg = lane >> 4;
    const int irow = i0 + lr;
    const int numJT = it16 / 4 + 1;

    if (threadIdx.x < 16) l_sm[threadIdx.x] = 0.f;
    __syncthreads();

    short8 q8[8];
    const short8* qp = (const short8*)(qf + (((size_t)b * 256 + it16) * 8) * 512);
#pragma unroll
    for (int kc = 0; kc < 8; ++kc) q8[kc] = qp[kc * 64 + lane];

    float rs = 0.f;
    {
        int jt = 0;
        for (; jt + 3 < numJT; jt += 4) {
            const short8* kp0 = (const short8*)(kf + (((size_t)b * 256 + jt * 4 + h) * 8) * 512);
            const short8* kp1 = kp0 + 2048;
            const short8* kp2 = kp0 + 4096;
            const short8* kp3 = kp0 + 6144;
            f32x4 a0 = {0.f,0.f,0.f,0.f}, a1 = a0, a2 = a0, a3 = a0;
#pragma unroll
            for (int kc = 0; kc < 8; ++kc) {
                a0 = mfma_k32(kp0[kc * 64 + lane], q8[kc], a0);
                a1 = mfma_k32(kp1[kc * 64 + lane], q8[kc], a1);
                a2 = mfma_k32(kp2[kc * 64 + lane], q8[kc], a2);
                a3 = mfma_k32(kp3[kc * 64 + lane], q8[kc], a3);
            }
            const int j00 = jt * 64 + 16 * h + 4 * lg;
#pragma unroll
            for (int r = 0; r < 4; ++r) {
                rs += (j00 + r       <= irow) ? __expf(a0[r] * 0.0625f) : 0.f;
                rs += (j00 + 64 + r  <= irow) ? __expf(a1[r] * 0.0625f) : 0.f;
                rs += (j00 + 128 + r <= irow) ? __expf(a2[r] * 0.0625f) : 0.f;
                rs += (j00 + 192 + r <= irow) ? __expf(a3[r] * 0.0625f) : 0.f;
            }
        }
        for (; jt + 1 < numJT; jt += 2) {
            const short8* kp0 = (const short8*)(kf + (((size_t)b * 256 + jt * 4 + h) * 8) * 512);
            const short8* kp1 = kp0 + 2048;
            f32x4 a0 = {0.f,0.f,0.f,0.f}, a1 = a0;
#pragma unroll
            for (int kc = 0; kc < 8; ++kc) {
                a0 = mfma_k32(kp0[kc * 64 + lane], q8[kc], a0);
                a1 = mfma_k32(kp1[kc * 64 + lane], q8[kc], a1);
            }
            const int j00 = jt * 64 + 16 * h + 4 * lg;
#pragma unroll
            for (int r = 0; r < 4; ++r) {
                rs += (j00 + r      <= irow) ? __expf(a0[r] * 0.0625f) : 0.f;
                rs += (j00 + 64 + r <= irow) ? __expf(a1[r] * 0.0625f) : 0.f;
            }
        }
        if (jt < numJT) {
            const short8* kp = (const short8*)(kf + (((size_t)b * 256 + jt * 4 + h) * 8) * 512);
            f32x4 a = {0.f,0.f,0.f,0.f};
#pragma unroll
            for (int kc = 0; kc < 8; ++kc)
                a = mfma_k32(kp[kc * 64 + lane], q8[kc], a);
            const int j0 = jt * 64 + 16 * h + 4 * lg;
#pragma unroll
            for (int r = 0; r < 4; ++r)
                rs += (j0 + r <= irow) ? __expf(a[r] * 0.0625f) : 0.f;
        }
    }
    rs += __shfl_xor(rs, 16, 64);
    rs += __shfl_xor(rs, 32, 64);
    if (lane < 16) atomicAdd(&l_sm[lr], rs);
    __syncthreads();
    if (threadIdx.x < 16)
        inv_ws[b * T_DIM + i0 + threadIdx.x] = 1.0f / l_sm[threadIdx.x];
}

// ---------------------------------------------------------------------------
// Kernel 3: attn write + PV (sweep-2 of R21), reading inv from inv_ws.
// Grid 256 x 512thr; block = (b, pair p/127-p), 8 waves = (f) x (h).
// Dual-jt + nf-pair 16B V loads + half-V hoist. Bare (512) bounds.
// ---------------------------------------------------------------------------
__global__ __launch_bounds__(512) void attn_kernel(
    const u16* __restrict__ qf, const u16* __restrict__ kf,
    const u16* __restrict__ vfw, const float* __restrict__ inv_ws,
    float* __restrict__ out) {
    __shared__ float O_sm[32 * 264];

    const int blk = blockIdx.x;
    const int xcd = blk & 7;                     // one b per XCD pair
    const int b = xcd >> 1, par = xcd & 1;
    const int pair = 2 * (blk >> 3) + par;       // 0..63

    const int tid = threadIdx.x;
    const int wid = tid >> 6, lane = tid & 63;
    const int f = wid >> 2, h = wid & 3;         // i-frag, j-quarter
    const int lr = lane & 15, lg = lane >> 4;

    float* attnO = out + (size_t)T_DIM * B_DIM * 256 + (size_t)b * T_DIM * T_DIM;

    for (int phase = 0; phase < 2; ++phase) {
        const int it = phase ? (127 - pair) : pair;   // 32-row i_tile, 0..127
        const int i0 = it * 32;
        const int irow = i0 + 16 * f + lr;
        const int numJT = it / 2 + 1;

        __syncthreads();                 // previous phase done with O_sm

        // Q fragments for this wave's i-frag (lane-contiguous)
        short8 q8[8];
        const short8* qp = (const short8*)(qf + (((size_t)b * 256 + it * 2 + f) * 8) * 512);
#pragma unroll
        for (int kc = 0; kc < 8; ++kc) q8[kc] = qp[kc * 64 + lane];

        const float inv = inv_ws[b * T_DIM + irow];

        // ---- attn write + PV, dual-jt + nf-pair 16B V loads ----
        f32x4 oacc[16];
#pragma unroll
        for (int nf = 0; nf < 16; ++nf) oacc[nf] = (f32x4){0.f,0.f,0.f,0.f};

        {
            int jt = 0;
            for (; jt + 1 < numJT; jt += 2) {
                const short8* kp0 = (const short8*)(kf + (((size_t)b * 256 + jt * 4 + h) * 8) * 512);
                const short8* kp1 = kp0 + 2048;
                const u16* vb0 = vfw + ((((size_t)b * 64 + jt) * 4 + h) * 4096)
                               + (size_t)lane * 8;
                const u16* vb1 = vb0 + 16384;

                // hoisted V loads (nf2 = 0..3 of both jt): overlap QK + exp
                short8 vpre0[4], vpre1[4];
#pragma unroll
                for (int nf2 = 0; nf2 < 4; ++nf2) {
                    vpre0[nf2] = *(const short8*)(vb0 + (size_t)nf2 * 512);
                    vpre1[nf2] = *(const short8*)(vb1 + (size_t)nf2 * 512);
                }

                short8 k0[8], k1[8];
#pragma unroll
                for (int kc = 0; kc < 8; ++kc) { k0[kc] = kp0[kc * 64 + lane]; k1[kc] = kp1[kc * 64 + lane]; }
                f32x4 a0 = {0.f,0.f,0.f,0.f}, a1 = a0;
#pragma unroll
                for (int kc = 0; kc < 8; ++kc) {
                    a0 = mfma_k32(k0[kc], q8[kc], a0);
                    a1 = mfma_k32(k1[kc], q8[kc], a1);
                }
                const int j00 = jt * 64 + 16 * h + 4 * lg;
#pragma unroll
                for (int r = 0; r < 4; ++r) {
                    a0[r] = (j00 + r      <= irow) ? __expf(a0[r] * 0.0625f) * inv : 0.f;
                    a1[r] = (j00 + 64 + r <= irow) ? __expf(a1[r] * 0.0625f) * inv : 0.f;
                }
                __builtin_nontemporal_store(a0, (f32x4*)(attnO + (size_t)irow * T_DIM + j00));
                __builtin_nontemporal_store(a1, (f32x4*)(attnO + (size_t)irow * T_DIM + j00 + 64));

                union { u16 u[4]; s16x4 v; } t0, t1;
#pragma unroll
                for (int r = 0; r < 4; ++r) { t0.u[r] = f2bf(a0[r]); t1.u[r] = f2bf(a1[r]); }
                const s16x4 pk0 = t0.v, pk1 = t1.v;

                // first half from prefetched registers
#pragma unroll
                for (int nf2 = 0; nf2 < 4; ++nf2) {
                    short8 v0 = vpre0[nf2];
                    short8 v1 = vpre1[nf2];
                    oacc[2*nf2]   = mfma_k16(pk0, __builtin_shufflevector(v0, v0, 0,1,2,3), oacc[2*nf2]);
                    oacc[2*nf2+1] = mfma_k16(pk0, __builtin_shufflevector(v0, v0, 4,5,6,7), oacc[2*nf2+1]);
                    oacc[2*nf2]   = mfma_k16(pk1, __builtin_shufflevector(v1, v1, 0,1,2,3), oacc[2*nf2]);
                    oacc[2*nf2+1] = mfma_k16(pk1, __builtin_shufflevector(v1, v1, 4,5,6,7), oacc[2*nf2+1]);
                }
                // second half loaded inline
#pragma unroll
                for (int nf2 = 4; nf2 < 8; ++nf2) {
                    short8 v0 = *(const short8*)(vb0 + (size_t)nf2 * 512);
                    short8 v1 = *(const short8*)(vb1 + (size_t)nf2 * 512);
                    oacc[2*nf2]   = mfma_k16(pk0, __builtin_shufflevector(v0, v0, 0,1,2,3), oacc[2*nf2]);
                    oacc[2*nf2+1] = mfma_k16(pk0, __builtin_shufflevector(v0, v0, 4,5,6,7), oacc[2*nf2+1]);
                    oacc[2*nf2]   = mfma_k16(pk1, __builtin_shufflevector(v1, v1, 0,1,2,3), oacc[2*nf2]);
                    oacc[2*nf2+1] = mfma_k16(pk1, __builtin_shufflevector(v1, v1, 4,5,6,7), oacc[2*nf2+1]);
                }
            }
            if (jt < numJT) {
                const short8* kp = (const short8*)(kf + (((size_t)b * 256 + jt * 4 + h) * 8) * 512);
                f32x4 a = {0.f,0.f,0.f,0.f};
#pragma unroll
                for (int kc = 0; kc < 8; ++kc)
                    a = mfma_k32(kp[kc * 64 + lane], q8[kc], a);
                const int j0 = jt * 64 + 16 * h + 4 * lg;
#pragma unroll
                for (int r = 0; r < 4; ++r)
                    a[r] = (j0 + r <= irow) ? __expf(a[r] * 0.0625f) * inv : 0.f;
                __builtin_nontemporal_store(a, (f32x4*)(attnO + (size_t)irow * T_DIM + j0));
                union { u16 u[4]; s16x4 v; } t;
#pragma unroll
                for (int r = 0; r < 4; ++r) t.u[r] = f2bf(a[r]);
                const s16x4 pk = t.v;
                const u16* vb = vfw + ((((size_t)b * 64 + jt) * 4 + h) * 4096)
                              + (size_t)lane * 8;
#pragma unroll
                for (int nf2 = 0; nf2 < 8; ++nf2) {
                    short8 v0 = *(const short8*)(vb + (size_t)nf2 * 512);
                    oacc[2*nf2]   = mfma_k16(pk, __builtin_shufflevector(v0, v0, 0,1,2,3), oacc[2*nf2]);
                    oacc[2*nf2+1] = mfma_k16(pk, __builtin_shufflevector(v0, v0, 4,5,6,7), oacc[2*nf2+1]);
                }
            }
        }

        // ---- combine the 4 j-quarter partials per i-frag via LDS ----
        for (int step = 0; step < 4; ++step) {
            if (h == step) {
#pragma unroll
                for (int nf = 0; nf < 16; ++nf)
#pragma unroll
                    for (int r = 0; r < 4; ++r) {
                        int row = 16 * f + 4 * lg + r, d = 16 * nf + lr;
                        if (step == 0) O_sm[row * 264 + d] = oacc[nf][r];
                        else           O_sm[row * 264 + d] += oacc[nf][r];
                    }
            }
            __syncthreads();
        }
        // store O -> results[t][b][d]
#pragma unroll
        for (int u = 0; u < 4; ++u) {
            int ix = tid + 512 * u;             // 0..2047
            int row = ix >> 6, c = ix & 63;     // 32 rows x 64 f32x4 chunks
            f32x4 v = *(const f32x4*)(O_sm + row * 264 + c * 4);
            __builtin_nontemporal_store(v,
                (f32x4*)(out + ((size_t)(i0 + row) * B_DIM + b) * 256 + c * 4));
        }
        __syncthreads();   // fence O_sm reads before any later LDS reuse

        // zero-fill strict upper triangle beyond computed tiles
        const int z0 = numJT * 64;
        if (z0 < T_DIM) {
            const int n4 = (T_DIM - z0) >> 2;
            for (int rr = 0; rr < 32; ++rr) {
                f32x4* rowp = (f32x4*)(attnO + (size_t)(i0 + rr) * T_DIM + z0);
                for (int c = tid; c < n4; c += 512) {
                    f32x4 z = {0.f, 0.f, 0.f, 0.f};
                    __builtin_nontemporal_store(z, rowp + c);
                }
            }
        }
    }
}

// ---------------------------------------------------------------------------
extern "C" void kernel_launch(void* const* d_in, const int* in_sizes, int n_in,
                              void* d_out, int out_size, void* d_ws, size_t ws_size,
                              hipStream_t stream) {
    (void)in_sizes; (void)n_in; (void)out_size; (void)ws_size;
    const float* X  = (const float*)d_in[0];
    const float* Wq = (const float*)d_in[1];
    const float* Wk = (const float*)d_in[2];
    const float* Wv = (const float*)d_in[3];
    float* out = (float*)d_out;

    char* ws = (char*)d_ws;
    u16* qf  = (u16*)(ws);                                  // 8 MB
    u16* kf  = (u16*)(ws + (size_t)8  * 1024 * 1024);       // 8 MB
    u16* vfw = (u16*)(ws + (size_t)16 * 1024 * 1024);       // 8 MB
    u16* wT  = (u16*)(ws + (size_t)24 * 1024 * 1024);       // 384 KB
    float* inv_ws = (float*)(ws + (size_t)25 * 1024 * 1024); // 64 KB

    wtrans_kernel<<<dim3(768), dim3(256), 0, stream>>>(Wq, Wk, Wv, wT);
    proj_kernel<<<dim3(1024), dim3(256), 0, stream>>>(X, wT, qf, kf, vfw);
    lsum_kernel<<<dim3(1024), dim3(256), 0, stream>>>(qf, kf, inv_ws);
    attn_kernel<<<dim3(256), dim3(512), 0, stream>>>(qf, kf, vfw, inv_ws, out);
}

// Round 28
// 206.263 us; speedup vs baseline: 1.1721x; 1.1721x over previous
//
#include <hip/hip_runtime.h>
#include <hip/hip_bf16.h>

#define T_DIM 4096
#define B_DIM 4

typedef unsigned short u16;
typedef __attribute__((ext_vector_type(4))) short s16x4;
typedef __attribute__((ext_vector_type(8))) short short8;
typedef __attribute__((ext_vector_type(8))) __bf16 bf16x8;
typedef __attribute__((ext_vector_type(4))) float f32x4;

static __device__ __forceinline__ u16 f2bf(float f) {
    union { float f; unsigned int u; } v; v.f = f;
    unsigned int u = v.u;
    u += 0x7FFFu + ((u >> 16) & 1u);   // RNE
    return (u16)(u >> 16);
}

static __device__ __forceinline__ f32x4 mfma_k32(short8 a, short8 b, f32x4 c) {
    return __builtin_amdgcn_mfma_f32_16x16x32_bf16(
        __builtin_bit_cast(bf16x8, a), __builtin_bit_cast(bf16x8, b), c, 0, 0, 0);
}
static __device__ __forceinline__ f32x4 mfma_k16(s16x4 a, s16x4 b, f32x4 c) {
    return __builtin_amdgcn_mfma_f32_16x16x16bf16_1k(a, b, c, 0, 0, 0);
}

// ---------------------------------------------------------------------------
// Kernel 0: transpose + convert weights to bf16 W^T[n][k]
// ---------------------------------------------------------------------------
__global__ __launch_bounds__(256) void wtrans_kernel(
    const float* __restrict__ Wq, const float* __restrict__ Wk,
    const float* __restrict__ Wv, u16* __restrict__ wT) {
    int idx = blockIdx.x * 256 + threadIdx.x;
    int w   = idx >> 16;
    int rem = idx & 65535;
    int k   = rem >> 8;
    int n   = rem & 255;
    const float* W = (w == 0) ? Wq : (w == 1) ? Wk : Wv;
    wT[w * 65536 + n * 256 + k] = f2bf(W[k * 256 + n]);
}

// ---------------------------------------------------------------------------
// Kernel 1: projection GEMM -> FRAGMENT-PACKED outputs.
//  qf/kf (u16): [b][tile=t/16][kc=0..7][lane][e=0..7]
//      = P[b][tile*16 + (lane&15)][kc*32 + (lane>>4)*8 + e]
//  vf  (u16): NF-PAIR layout (one 16B load feeds two k16 B-frags):
//      [b][jt=t/64][h=0..3][nf2=0..7][lane][e=0..7]
//      = V[b][jt*64 + 16*h + 4*(lane>>4) + (e&3)][ (2*nf2 + e/4)*16 + (lane&15) ]
// ---------------------------------------------------------------------------
__global__ __launch_bounds__(256, 4) void proj_kernel(
    const float* __restrict__ X, const u16* __restrict__ wT,
    u16* __restrict__ qf, u16* __restrict__ kf, u16* __restrict__ vfw) {
    const int r0  = blockIdx.x * 16;
    const int wid = threadIdx.x >> 6, lane = threadIdx.x & 63;
    const int lr  = lane & 15, lg = lane >> 4;

    short8 af[8];
    const float* xrow = X + (size_t)(r0 + lr) * 256 + lg * 8;
#pragma unroll
    for (int kc = 0; kc < 8; ++kc) {
        f32x4 xa = *(const f32x4*)(xrow + kc * 32);
        f32x4 xb = *(const f32x4*)(xrow + kc * 32 + 4);
        union { u16 u[8]; short8 v; } t;
#pragma unroll
        for (int e = 0; e < 4; ++e) { t.u[e] = f2bf(xa[e]); t.u[4 + e] = f2bf(xb[e]); }
        af[kc] = t.v;
    }

    for (int w = 0; w < 3; ++w) {
        f32x4 acc[4];
#pragma unroll
        for (int nf = 0; nf < 4; ++nf) acc[nf] = (f32x4){0.f,0.f,0.f,0.f};
        const u16* wbase = wT + w * 65536 + (size_t)(16 * (4 * wid) + lr) * 256 + lg * 8;
#pragma unroll
        for (int kc = 0; kc < 8; ++kc)
#pragma unroll
            for (int nf = 0; nf < 4; ++nf) {
                short8 bfv = *(const short8*)(wbase + nf * 16 * 256 + kc * 32);
                acc[nf] = mfma_k32(af[kc], bfv, acc[nf]);
            }
#pragma unroll
        for (int nf = 0; nf < 4; ++nf)
#pragma unroll
            for (int r = 0; r < 4; ++r) {
                int rg = r0 + 4 * lg + r;
                int t  = rg >> 2, bb = rg & 3;           // X rows are (t, b)
                int d  = 16 * (4 * wid + nf) + lr;
                u16 val = f2bf(acc[nf][r]);
                if (w < 2) {
                    int tile = t >> 4, lrq = t & 15;
                    int kc = d >> 5, lgq = (d >> 3) & 3, e = d & 7;
                    size_t idx = ((((size_t)bb * 256 + tile) * 8 + kc) * 64
                                  + lrq + 16 * lgq) * 8 + e;
                    if (w == 0) qf[idx] = val; else kf[idx] = val;
                } else {
                    int jt = t >> 6, hh = (t >> 4) & 3;
                    int lgv = (t >> 2) & 3, el = t & 3;
                    int nfv = d >> 4, lrv = d & 15;
                    int lanev = lrv + 16 * lgv;
                    size_t idx = (((((size_t)bb * 64 + jt) * 4 + hh) * 8 + (nfv >> 1)) * 64
                                  + lanev) * 8 + (nfv & 1) * 4 + el;
                    vfw[idx] = val;
                }
            }
    }
}

// ---------------------------------------------------------------------------
// Kernel 2: fused causal attention (R21 = verified best, ~207us total,
// reproduced three times). Grid 256 x 512thr; block = (b, pair p/127-p),
// 8 waves = (f: i-frag) x (h: j-quarter), same-jt walk. Sweep1: quad-jt QK
// unroll. Sweep2: dual-jt + nf-pair 16B V loads + half-V hoist. Bare (512)
// bounds. PLATEAU: quad-sweep2 (R20), s-split+osum (R16), deferred-norm
// (R22), K-prefetch-rotate (R24, spilled), lsum-split (R26) all regressed;
// (512,2) bounds raced (R17). Body must stay under ~128 live VGPRs.
// ---------------------------------------------------------------------------
__global__ __launch_bounds__(512) void attn_kernel(
    const u16* __restrict__ qf, const u16* __restrict__ kf,
    const u16* __restrict__ vfw, float* __restrict__ out) {
    __shared__ float l_sm[32];
    __shared__ float O_sm[32 * 264];

    const int blk = blockIdx.x;
    const int xcd = blk & 7;                     // one b per XCD pair
    const int b = xcd >> 1, par = xcd & 1;
    const int pair = 2 * (blk >> 3) + par;       // 0..63

    const int tid = threadIdx.x;
    const int wid = tid >> 6, lane = tid & 63;
    const int f = wid >> 2, h = wid & 3;         // i-frag, j-quarter
    const int lr = lane & 15, lg = lane >> 4;

    float* attnO = out + (size_t)T_DIM * B_DIM * 256 + (size_t)b * T_DIM * T_DIM;

    for (int phase = 0; phase < 2; ++phase) {
        const int it = phase ? (127 - pair) : pair;   // 32-row i_tile, 0..127
        const int i0 = it * 32;
        const int irow = i0 + 16 * f + lr;
        const int numJT = it / 2 + 1;

        __syncthreads();                 // previous phase done with LDS
        if (tid < 32) l_sm[tid] = 0.f;
        __syncthreads();

        // Q fragments for this wave's i-frag (lane-contiguous)
        short8 q8[8];
        const short8* qp = (const short8*)(qf + (((size_t)b * 256 + it * 2 + f) * 8) * 512);
#pragma unroll
        for (int kc = 0; kc < 8; ++kc) q8[kc] = qp[kc * 64 + lane];

        // ---- sweep 1: row sums of exp(S), quad-jt unrolled ----
        float rs = 0.f;
        {
            int jt = 0;
            for (; jt + 3 < numJT; jt += 4) {
                const short8* kp0 = (const short8*)(kf + (((size_t)b * 256 + jt * 4 + h) * 8) * 512);
                const short8* kp1 = kp0 + 2048;
                const short8* kp2 = kp0 + 4096;
                const short8* kp3 = kp0 + 6144;
                f32x4 a0 = {0.f,0.f,0.f,0.f}, a1 = a0, a2 = a0, a3 = a0;
#pragma unroll
                for (int kc = 0; kc < 8; ++kc) {
                    a0 = mfma_k32(kp0[kc * 64 + lane], q8[kc], a0);
                    a1 = mfma_k32(kp1[kc * 64 + lane], q8[kc], a1);
                    a2 = mfma_k32(kp2[kc * 64 + lane], q8[kc], a2);
                    a3 = mfma_k32(kp3[kc * 64 + lane], q8[kc], a3);
                }
                const int j00 = jt * 64 + 16 * h + 4 * lg;
#pragma unroll
                for (int r = 0; r < 4; ++r) {
                    rs += (j00 + r       <= irow) ? __expf(a0[r] * 0.0625f) : 0.f;
                    rs += (j00 + 64 + r  <= irow) ? __expf(a1[r] * 0.0625f) : 0.f;
                    rs += (j00 + 128 + r <= irow) ? __expf(a2[r] * 0.0625f) : 0.f;
                    rs += (j00 + 192 + r <= irow) ? __expf(a3[r] * 0.0625f) : 0.f;
                }
            }
            for (; jt + 1 < numJT; jt += 2) {
                const short8* kp0 = (const short8*)(kf + (((size_t)b * 256 + jt * 4 + h) * 8) * 512);
                const short8* kp1 = kp0 + 2048;
                f32x4 a0 = {0.f,0.f,0.f,0.f}, a1 = a0;
#pragma unroll
                for (int kc = 0; kc < 8; ++kc) {
                    a0 = mfma_k32(kp0[kc * 64 + lane], q8[kc], a0);
                    a1 = mfma_k32(kp1[kc * 64 + lane], q8[kc], a1);
                }
                const int j00 = jt * 64 + 16 * h + 4 * lg;
#pragma unroll
                for (int r = 0; r < 4; ++r) {
                    rs += (j00 + r      <= irow) ? __expf(a0[r] * 0.0625f) : 0.f;
                    rs += (j00 + 64 + r <= irow) ? __expf(a1[r] * 0.0625f) : 0.f;
                }
            }
            if (jt < numJT) {
                const short8* kp = (const short8*)(kf + (((size_t)b * 256 + jt * 4 + h) * 8) * 512);
                f32x4 a = {0.f,0.f,0.f,0.f};
#pragma unroll
                for (int kc = 0; kc < 8; ++kc)
                    a = mfma_k32(kp[kc * 64 + lane], q8[kc], a);
                const int j0 = jt * 64 + 16 * h + 4 * lg;
#pragma unroll
                for (int r = 0; r < 4; ++r)
                    rs += (j0 + r <= irow) ? __expf(a[r] * 0.0625f) : 0.f;
            }
        }
        rs += __shfl_xor(rs, 16, 64);
        rs += __shfl_xor(rs, 32, 64);
        if (lane < 16) atomicAdd(&l_sm[16 * f + lr], rs);
        __syncthreads();
        const float inv = 1.0f / l_sm[16 * f + lr];

        // ---- sweep 2: attn write + PV, dual-jt + nf-pair 16B V loads ----
        f32x4 oacc[16];
#pragma unroll
        for (int nf = 0; nf < 16; ++nf) oacc[nf] = (f32x4){0.f,0.f,0.f,0.f};

        {
            int jt = 0;
            for (; jt + 1 < numJT; jt += 2) {
                const short8* kp0 = (const short8*)(kf + (((size_t)b * 256 + jt * 4 + h) * 8) * 512);
                const short8* kp1 = kp0 + 2048;
                const u16* vb0 = vfw + ((((size_t)b * 64 + jt) * 4 + h) * 4096)
                               + (size_t)lane * 8;
                const u16* vb1 = vb0 + 16384;

                // hoisted V loads (nf2 = 0..3 of both jt): overlap QK + exp
                short8 vpre0[4], vpre1[4];
#pragma unroll
                for (int nf2 = 0; nf2 < 4; ++nf2) {
                    vpre0[nf2] = *(const short8*)(vb0 + (size_t)nf2 * 512);
                    vpre1[nf2] = *(const short8*)(vb1 + (size_t)nf2 * 512);
                }

                short8 k0[8], k1[8];
#pragma unroll
                for (int kc = 0; kc < 8; ++kc) { k0[kc] = kp0[kc * 64 + lane]; k1[kc] = kp1[kc * 64 + lane]; }
                f32x4 a0 = {0.f,0.f,0.f,0.f}, a1 = a0;
#pragma unroll
                for (int kc = 0; kc < 8; ++kc) {
                    a0 = mfma_k32(k0[kc], q8[kc], a0);
                    a1 = mfma_k32(k1[kc], q8[kc], a1);
                }
                const int j00 = jt * 64 + 16 * h + 4 * lg;
#pragma unroll
                for (int r = 0; r < 4; ++r) {
                    a0[r] = (j00 + r      <= irow) ? __expf(a0[r] * 0.0625f) * inv : 0.f;
                    a1[r] = (j00 + 64 + r <= irow) ? __expf(a1[r] * 0.0625f) * inv : 0.f;
                }
                __builtin_nontemporal_store(a0, (f32x4*)(attnO + (size_t)irow * T_DIM + j00));
                __builtin_nontemporal_store(a1, (f32x4*)(attnO + (size_t)irow * T_DIM + j00 + 64));

                union { u16 u[4]; s16x4 v; } t0, t1;
#pragma unroll
                for (int r = 0; r < 4; ++r) { t0.u[r] = f2bf(a0[r]); t1.u[r] = f2bf(a1[r]); }
                const s16x4 pk0 = t0.v, pk1 = t1.v;

                // first half from prefetched registers
#pragma unroll
                for (int nf2 = 0; nf2 < 4; ++nf2) {
                    short8 v0 = vpre0[nf2];
                    short8 v1 = vpre1[nf2];
                    oacc[2*nf2]   = mfma_k16(pk0, __builtin_shufflevector(v0, v0, 0,1,2,3), oacc[2*nf2]);
                    oacc[2*nf2+1] = mfma_k16(pk0, __builtin_shufflevector(v0, v0, 4,5,6,7), oacc[2*nf2+1]);
                    oacc[2*nf2]   = mfma_k16(pk1, __builtin_shufflevector(v1, v1, 0,1,2,3), oacc[2*nf2]);
                    oacc[2*nf2+1] = mfma_k16(pk1, __builtin_shufflevector(v1, v1, 4,5,6,7), oacc[2*nf2+1]);
                }
                // second half loaded inline
#pragma unroll
                for (int nf2 = 4; nf2 < 8; ++nf2) {
                    short8 v0 = *(const short8*)(vb0 + (size_t)nf2 * 512);
                    short8 v1 = *(const short8*)(vb1 + (size_t)nf2 * 512);
                    oacc[2*nf2]   = mfma_k16(pk0, __builtin_shufflevector(v0, v0, 0,1,2,3), oacc[2*nf2]);
                    oacc[2*nf2+1] = mfma_k16(pk0, __builtin_shufflevector(v0, v0, 4,5,6,7), oacc[2*nf2+1]);
                    oacc[2*nf2]   = mfma_k16(pk1, __builtin_shufflevector(v1, v1, 0,1,2,3), oacc[2*nf2]);
                    oacc[2*nf2+1] = mfma_k16(pk1, __builtin_shufflevector(v1, v1, 4,5,6,7), oacc[2*nf2+1]);
                }
            }
            if (jt < numJT) {
                const short8* kp = (const short8*)(kf + (((size_t)b * 256 + jt * 4 + h) * 8) * 512);
                f32x4 a = {0.f,0.f,0.f,0.f};
#pragma unroll
                for (int kc = 0; kc < 8; ++kc)
                    a = mfma_k32(kp[kc * 64 + lane], q8[kc], a);
                const int j0 = jt * 64 + 16 * h + 4 * lg;
#pragma unroll
                for (int r = 0; r < 4; ++r)
                    a[r] = (j0 + r <= irow) ? __expf(a[r] * 0.0625f) * inv : 0.f;
                __builtin_nontemporal_store(a, (f32x4*)(attnO + (size_t)irow * T_DIM + j0));
                union { u16 u[4]; s16x4 v; } t;
#pragma unroll
                for (int r = 0; r < 4; ++r) t.u[r] = f2bf(a[r]);
                const s16x4 pk = t.v;
                const u16* vb = vfw + ((((size_t)b * 64 + jt) * 4 + h) * 4096)
                              + (size_t)lane * 8;
#pragma unroll
                for (int nf2 = 0; nf2 < 8; ++nf2) {
                    short8 v0 = *(const short8*)(vb + (size_t)nf2 * 512);
                    oacc[2*nf2]   = mfma_k16(pk, __builtin_shufflevector(v0, v0, 0,1,2,3), oacc[2*nf2]);
                    oacc[2*nf2+1] = mfma_k16(pk, __builtin_shufflevector(v0, v0, 4,5,6,7), oacc[2*nf2+1]);
                }
            }
        }

        // ---- combine the 4 j-quarter partials per i-frag via LDS ----
        for (int step = 0; step < 4; ++step) {
            if (h == step) {
#pragma unroll
                for (int nf = 0; nf < 16; ++nf)
#pragma unroll
                    for (int r = 0; r < 4; ++r) {
                        int row = 16 * f + 4 * lg + r, d = 16 * nf + lr;
                        if (step == 0) O_sm[row * 264 + d] = oacc[nf][r];
                        else           O_sm[row * 264 + d] += oacc[nf][r];
                    }
            }
            __syncthreads();
        }
        // store O -> results[t][b][d]
#pragma unroll
        for (int u = 0; u < 4; ++u) {
            int ix = tid + 512 * u;             // 0..2047
            int row = ix >> 6, c = ix & 63;     // 32 rows x 64 f32x4 chunks
            f32x4 v = *(const f32x4*)(O_sm + row * 264 + c * 4);
            __builtin_nontemporal_store(v,
                (f32x4*)(out + ((size_t)(i0 + row) * B_DIM + b) * 256 + c * 4));
        }
        __syncthreads();   // fence O_sm reads before any later LDS reuse

        // zero-fill strict upper triangle beyond computed tiles
        const int z0 = numJT * 64;
        if (z0 < T_DIM) {
            const int n4 = (T_DIM - z0) >> 2;
            for (int rr = 0; rr < 32; ++rr) {
                f32x4* rowp = (f32x4*)(attnO + (size_t)(i0 + rr) * T_DIM + z0);
                for (int c = tid; c < n4; c += 512) {
                    f32x4 z = {0.f, 0.f, 0.f, 0.f};
                    __builtin_nontemporal_store(z, rowp + c);
                }
            }
        }
    }
}

// ---------------------------------------------------------------------------
extern "C" void kernel_launch(void* const* d_in, const int* in_sizes, int n_in,
                              void* d_out, int out_size, void* d_ws, size_t ws_size,
                              hipStream_t stream) {
    (void)in_sizes; (void)n_in; (void)out_size; (void)ws_size;
    const float* X  = (const float*)d_in[0];
    const float* Wq = (const float*)d_in[1];
    const float* Wk = (const float*)d_in[2];
    const float* Wv = (const float*)d_in[3];
    float* out = (float*)d_out;

    char* ws = (char*)d_ws;
    u16* qf  = (u16*)(ws);                                  // 8 MB
    u16* kf  = (u16*)(ws + (size_t)8  * 1024 * 1024);       // 8 MB
    u16* vfw = (u16*)(ws + (size_t)16 * 1024 * 1024);       // 8 MB
    u16* wT  = (u16*)(ws + (size_t)24 * 1024 * 1024);       // 384 KB

    wtrans_kernel<<<dim3(768), dim3(256), 0, stream>>>(Wq, Wk, Wv, wT);
    proj_kernel<<<dim3(1024), dim3(256), 0, stream>>>(X, wT, qf, kf, vfw);
    attn_kernel<<<dim3(256), dim3(512), 0, stream>>>(qf, kf, vfw, out);
}